// Round 3
// baseline (252.492 us; speedup 1.0000x reference)
//
#include <hip/hip_runtime.h>
#include <hip/hip_bf16.h>

#ifndef BN_EPS
#define BN_EPS 1e-5f
#endif

// ---------------------------------------------------------------------------
// N=100000, C=64, E=1600000.
// R14: R13 structure + pre-scaled rows (xb2 = bf16(dinv[src]*x)), single pass.
//   R13 post-mortem: deeper ILP gained ~0 -> k_agg is bound by per-CU
//   in-flight request slots; time ~ sum(line-requests x latency). The
//   per-edge dinv gather (16 L2-hit lines/node, on the dependence chain) is
//   ~15% of that budget. Pre-scaling removes it + all w-shuffles.
//   deg comes free from k_csr's LDS histogram -> conversion folded into
//   k_csr (its block owns the 128 nodes it histograms). No global atomics,
//   no extra dispatch. Tail masking via zero row at index N (k_scanSub).
// 8 dispatches: memset, pre(bin), scanSub, sub, csr(+conv), agg, gemm1, gemm2.
// bias cancels inside BatchNorm, skipped.
// ---------------------------------------------------------------------------

#define NPB 8192
#define NPB_SHIFT 13

__device__ __forceinline__ unsigned short f2bf(float f) {
    unsigned u = __float_as_uint(f);
    u += 0x7FFF + ((u >> 16) & 1);  // round-to-nearest-even
    return (unsigned short)(u >> 16);
}
__device__ __forceinline__ float bf2f(unsigned v) {
    return __uint_as_float(v << 16);
}

// Coarse 13-bucket LDS chunk-sort (slack-capacity regions, cursor in bcnt) +
// 832-subbucket histogram (cnt2).
__global__ __launch_bounds__(256) void k_pre(const int* __restrict__ src,
                                             const int* __restrict__ dst,
                                             int* __restrict__ cnt2,
                                             int* __restrict__ bcnt,
                                             unsigned* __restrict__ binned,
                                             int E, int SUBTOT, int cap) {
    __shared__ int hist[16], hexcl[16], hcur[16], gbase[16];
    __shared__ int h2[1024];
    __shared__ unsigned lout[4096];
    __shared__ unsigned char lb[4096];
    int tid = threadIdx.x;
    int c0 = blockIdx.x * 4096;
    if (c0 >= E) return;
    int cnt = min(4096, E - c0);
    if (tid < 16) hist[tid] = 0;
    for (int i = tid; i < SUBTOT; i += 256) h2[i] = 0;
    __syncthreads();
    for (int i = tid; i < cnt; i += 256) {
        int d = dst[c0 + i];
        atomicAdd(&hist[d >> NPB_SHIFT], 1);
        atomicAdd(&h2[d >> 7], 1);
    }
    __syncthreads();
    if (tid == 0) {
        int acc = 0;
        for (int b = 0; b < 16; b++) { hexcl[b] = acc; hcur[b] = acc; acc += hist[b]; }
    }
    __syncthreads();
    if (tid < 16 && hist[tid] > 0) gbase[tid] = atomicAdd(&bcnt[tid], hist[tid]);
    for (int i = tid; i < SUBTOT; i += 256) {
        int v = h2[i];
        if (v > 0) atomicAdd(&cnt2[i], v);
    }
    for (int i = tid; i < cnt; i += 256) {
        int d = dst[c0 + i];
        int s = src[c0 + i];
        int b = d >> NPB_SHIFT;
        unsigned packed = (unsigned)s | ((unsigned)(d & (NPB - 1)) << 17);
        int p = atomicAdd(&hcur[b], 1);
        lout[p] = packed;
        lb[p] = (unsigned char)b;
    }
    __syncthreads();
    for (int i = tid; i < cnt; i += 256) {
        int b = lb[i];
        binned[(size_t)b * cap + gbase[b] + (i - hexcl[b])] = lout[i];
    }
}

// Exact scan of cnt2 -> sbase (excl, +sentinel), scur copy; zeroes stats and
// the zero row xb2[N] (gather target for masked tail lanes in k_agg).
__global__ __launch_bounds__(1024) void k_scanSub(const int* __restrict__ cnt2,
                                                  int* __restrict__ sbase,
                                                  int* __restrict__ scur,
                                                  float* __restrict__ stats,
                                                  unsigned* __restrict__ xbz,
                                                  int SUBTOT, int E) {
    __shared__ int s[1024];
    int t = threadIdx.x;
    if (t < 128) stats[t] = 0.f;
    if (t < 32) xbz[t] = 0u;
    int v = (t < SUBTOT) ? cnt2[t] : 0;
    s[t] = v;
    __syncthreads();
    for (int off = 1; off < 1024; off <<= 1) {
        int add = (t >= off) ? s[t - off] : 0;
        __syncthreads();
        s[t] += add;
        __syncthreads();
    }
    if (t < SUBTOT) {
        int excl = s[t] - v;
        sbase[t] = excl;
        scur[t] = excl;
    }
    if (t == 0) sbase[SUBTOT] = E;
}

// Per coarse bucket (32 blocks each): chunk-sort into 64 sub-buckets at exact
// scur offsets. in: binned region [b*cap, b*cap+total). out: src | local7<<17.
__global__ __launch_bounds__(256) void k_sub(const unsigned* __restrict__ binned,
                                             const int* __restrict__ sbase,
                                             int* __restrict__ scur,
                                             unsigned* __restrict__ sorted2,
                                             int cap, int B) {
    __shared__ int hist[64], hexcl[64], hcur[64], gbase[64];
    __shared__ unsigned lout[4096];
    __shared__ unsigned char lb[4096];
    int b = blockIdx.x >> 5;
    int r = blockIdx.x & 31;
    if (b >= B) return;
    int tid = threadIdx.x;
    int total = sbase[(b + 1) << 6] - sbase[b << 6];
    const unsigned* bb = binned + (size_t)b * cap;
    for (int c0 = r * 4096; c0 < total; c0 += 32 * 4096) {
        int cnt = min(4096, total - c0);
        if (tid < 64) hist[tid] = 0;
        __syncthreads();
        for (int i = tid; i < cnt; i += 256)
            atomicAdd(&hist[(bb[c0 + i] >> 24) & 63], 1);  // local13>>7
        __syncthreads();
        if (tid == 0) {
            int acc = 0;
            for (int f = 0; f < 64; f++) { hexcl[f] = acc; hcur[f] = acc; acc += hist[f]; }
        }
        __syncthreads();
        if (tid < 64 && hist[tid] > 0)
            gbase[tid] = atomicAdd(&scur[(b << 6) + tid], hist[tid]);
        for (int i = tid; i < cnt; i += 256) {
            unsigned e = bb[c0 + i];
            int f = (e >> 24) & 63;
            unsigned rp = (e & 0x1FFFFu) | (((e >> 17) & 127u) << 17);
            int p = atomicAdd(&hcur[f], 1);
            lout[p] = rp;
            lb[p] = (unsigned char)f;
        }
        __syncthreads();
        for (int i = tid; i < cnt; i += 256) {
            int f = lb[i];
            sorted2[gbase[f] + (i - hexcl[f])] = lout[i];
        }
        __syncthreads();
    }
}

// One block per 128-node sub-bucket: private csr window scatter + deg/dinv/
// offs from the LDS histogram + conversion of this block's own 128 rows:
// xb2[n] = bf16(dinv[n] * x[n]) (pre-scaled by source norm).
__global__ __launch_bounds__(256) void k_csr(const unsigned* __restrict__ sorted2,
                                             const int* __restrict__ sbase,
                                             const float* __restrict__ x,
                                             int* __restrict__ deg,
                                             float* __restrict__ dinv,
                                             int* __restrict__ offs,
                                             int* __restrict__ csr,
                                             unsigned short* __restrict__ xb2,
                                             int N) {
    __shared__ int hist[128], lbase[128], lcur[128];
    __shared__ float sdinv[128];
    int s = blockIdx.x;
    int j0 = sbase[s], j1 = sbase[s + 1];
    int tid = threadIdx.x;
    if (tid < 128) { hist[tid] = 0; lcur[tid] = 0; }
    __syncthreads();
    for (int j = j0 + tid; j < j1; j += 256)
        atomicAdd(&hist[sorted2[j] >> 17], 1);
    __syncthreads();
    if (tid == 0) {
        int acc = 0;
        for (int k = 0; k < 128; k++) { lbase[k] = acc; acc += hist[k]; }
    }
    __syncthreads();
    if (tid < 128) {  // deg / dinv / offs for this sub-bucket's 128 nodes
        int n = (s << 7) + tid;
        float dn = rsqrtf((float)(hist[tid] + 1));  // +1 = self-loop
        sdinv[tid] = dn;
        if (n < N) {
            deg[n] = hist[tid];
            dinv[n] = dn;
            offs[n] = j0 + lbase[tid];  // csr is globally dst-ordered
        }
    }
    __syncthreads();
    for (int j = j0 + tid; j < j1; j += 256) {
        unsigned e = sorted2[j];
        int ld = e >> 17;
        int pos = j0 + lbase[ld] + atomicAdd(&lcur[ld], 1);
        csr[pos] = (int)(e & 0x1FFFFu);
    }
    // Convert this block's 128 rows (streaming 32KB read, 16KB write).
    int base = s << 11;  // s*128 nodes * 16 float4/row
    const float4* xp = (const float4*)x;
    ushort4* xbp = (ushort4*)xb2;
#pragma unroll
    for (int i = 0; i < 8; i++) {
        int idx = tid + 256 * i;
        int n = (s << 7) + (idx >> 4);
        if (n < N) {
            float dn = sdinv[idx >> 4];
            float4 v = xp[base + idx];
            ushort4 b;
            b.x = f2bf(v.x * dn); b.y = f2bf(v.y * dn);
            b.z = f2bf(v.z * dn); b.w = f2bf(v.w * dn);
            xbp[base + idx] = b;
        }
    }
}

// Wave per node. lane = (half h, channel-pair p): one 4B load = 2 channels of
// one of 2 edges. 16-edge groups, 8 gathers in flight. Rows pre-scaled by
// dinv[src] -> plain adds, no weight gather/shuffle. Lanes >= cnt hold
// idx=N (zero row, L1-hot) -- no serialized tails, no masking.
__global__ __launch_bounds__(256) void k_agg(const int* __restrict__ offs,
                                             const int* __restrict__ deg,
                                             const int* __restrict__ csr,
                                             const unsigned short* __restrict__ xb2,
                                             const float* __restrict__ dinv,
                                             unsigned* __restrict__ aggb32, int N) {
    int lane = threadIdx.x & 63;
    int p = lane & 31;   // channel pair (channels 2p, 2p+1)
    int h = lane >> 5;   // half: which edge of a pair this lane gathers
    int wid = (blockIdx.x * 256 + threadIdx.x) >> 6;
    int nw = (gridDim.x * 256) >> 6;
    const unsigned* xw = (const unsigned*)xb2;

    for (int n = wid; n < N; n += nw) {
        float dn = dinv[n];
        unsigned sv = xw[(size_t)n * 32 + p];  // pre-scaled self row
        float accx = (h == 0) ? bf2f(sv & 0xFFFFu) : 0.f;
        float accy = (h == 0) ? bf2f(sv >> 16) : 0.f;
        int j0 = offs[n];
        int j1 = j0 + deg[n];
        for (int jb = j0; jb < j1; jb += 64) {
            int cnt = min(64, j1 - jb);
            int idx = N;  // zero row for overshoot lanes
            if (lane < cnt) idx = csr[jb + lane];
            for (int j = 0; j < cnt; j += 16) {
                int s0 = __shfl(idx, j + 0 + h),  s1 = __shfl(idx, j + 2 + h);
                int s2 = __shfl(idx, j + 4 + h),  s3 = __shfl(idx, j + 6 + h);
                int s4 = __shfl(idx, j + 8 + h),  s5 = __shfl(idx, j + 10 + h);
                int s6 = __shfl(idx, j + 12 + h), s7 = __shfl(idx, j + 14 + h);
                unsigned v0 = xw[(size_t)s0 * 32 + p];
                unsigned v1 = xw[(size_t)s1 * 32 + p];
                unsigned v2 = xw[(size_t)s2 * 32 + p];
                unsigned v3 = xw[(size_t)s3 * 32 + p];
                unsigned v4 = xw[(size_t)s4 * 32 + p];
                unsigned v5 = xw[(size_t)s5 * 32 + p];
                unsigned v6 = xw[(size_t)s6 * 32 + p];
                unsigned v7 = xw[(size_t)s7 * 32 + p];
                accx += bf2f(v0 & 0xFFFFu); accy += bf2f(v0 >> 16);
                accx += bf2f(v1 & 0xFFFFu); accy += bf2f(v1 >> 16);
                accx += bf2f(v2 & 0xFFFFu); accy += bf2f(v2 >> 16);
                accx += bf2f(v3 & 0xFFFFu); accy += bf2f(v3 >> 16);
                accx += bf2f(v4 & 0xFFFFu); accy += bf2f(v4 >> 16);
                accx += bf2f(v5 & 0xFFFFu); accy += bf2f(v5 >> 16);
                accx += bf2f(v6 & 0xFFFFu); accy += bf2f(v6 >> 16);
                accx += bf2f(v7 & 0xFFFFu); accy += bf2f(v7 >> 16);
            }
        }
        accx += __shfl_xor(accx, 32);
        accy += __shfl_xor(accy, 32);
        if (h == 0) {
            unsigned o = (unsigned)f2bf(accx * dn) | ((unsigned)f2bf(accy * dn) << 16);
            aggb32[(size_t)n * 32 + p] = o;
        }
    }
}

// Stats pass: o = agg@W per row (same structure as k_gemm2, NO stores).
__global__ __launch_bounds__(256) void k_gemm1(const unsigned* __restrict__ aggb32,
                                               const float* __restrict__ W,
                                               float* __restrict__ stats, int N) {
    __shared__ unsigned tile[256 * 32];
    __shared__ float red[512];  // [2][4][64]
    int t = threadIdx.x;
    int lane = t & 63;
    int w = t >> 6;
    int r0 = blockIdx.x * 256;
    const uint4* gp = (const uint4*)(aggb32 + (size_t)r0 * 32);
#pragma unroll
    for (int i = 0; i < 8; i++) {
        int idx = t + 256 * i;
        int n = r0 + (idx >> 3);
        uint4 v = {0u, 0u, 0u, 0u};
        if (n < N) v = gp[idx];
        *(uint4*)(tile + idx * 4) = v;
    }
    float wcol[64];
#pragma unroll
    for (int k = 0; k < 64; k++) wcol[k] = W[k * 64 + lane];
    __syncthreads();

    float psum = 0.f, psq = 0.f;
    for (int rr = 0; rr < 64; rr += 2) {
        int lr0 = w * 64 + rr;
        int n0 = r0 + lr0;
        if (n0 >= N) break;
        const unsigned* row0 = tile + lr0 * 32;
        const unsigned* row1 = row0 + 32;
        float o0 = 0.f, o1 = 0.f;
#pragma unroll
        for (int kp = 0; kp < 32; kp++) {
            unsigned u0 = row0[kp], u1 = row1[kp];
            o0 = fmaf(bf2f(u0 & 0xFFFFu), wcol[2 * kp], o0);
            o0 = fmaf(bf2f(u0 >> 16), wcol[2 * kp + 1], o0);
            o1 = fmaf(bf2f(u1 & 0xFFFFu), wcol[2 * kp], o1);
            o1 = fmaf(bf2f(u1 >> 16), wcol[2 * kp + 1], o1);
        }
        psum += o0;
        psq = fmaf(o0, o0, psq);
        if (n0 + 1 < N) {
            psum += o1;
            psq = fmaf(o1, o1, psq);
        }
    }
    red[w * 64 + lane] = psum;
    red[256 + w * 64 + lane] = psq;
    __syncthreads();
    if (w == 0) {
        float s = red[lane] + red[64 + lane] + red[128 + lane] + red[192 + lane];
        atomicAdd(&stats[lane], s);
    } else if (w == 1) {
        float q = red[256 + lane] + red[320 + lane] + red[384 + lane] + red[448 + lane];
        atomicAdd(&stats[64 + lane], q);
    }
}

// out = BN(agg@W)+ReLU, BN scale/shift derived in-prologue from stats.
__global__ __launch_bounds__(256) void k_gemm2(const unsigned* __restrict__ aggb32,
                                               const float* __restrict__ W,
                                               const float* __restrict__ stats,
                                               const float* __restrict__ gamma,
                                               const float* __restrict__ beta,
                                               float* __restrict__ out, int N,
                                               float invN) {
    __shared__ unsigned tile[256 * 32];
    __shared__ float ssl[128];
    int t = threadIdx.x;
    int lane = t & 63;
    int w = t >> 6;
    int r0 = blockIdx.x * 256;
    const uint4* gp = (const uint4*)(aggb32 + (size_t)r0 * 32);
#pragma unroll
    for (int i = 0; i < 8; i++) {
        int idx = t + 256 * i;
        int n = r0 + (idx >> 3);
        uint4 v = {0u, 0u, 0u, 0u};
        if (n < N) v = gp[idx];
        *(uint4*)(tile + idx * 4) = v;
    }
    if (t < 64) {  // bnprep folded in (redundant per block, trivial)
        float mean = stats[t] * invN;
        float var = stats[64 + t] * invN - mean * mean;  // biased var
        float sc = gamma[t] * rsqrtf(var + BN_EPS);
        ssl[t] = sc;
        ssl[64 + t] = beta[t] - mean * sc;
    }
    float wcol[64];
#pragma unroll
    for (int k = 0; k < 64; k++) wcol[k] = W[k * 64 + lane];
    __syncthreads();
    float sc = ssl[lane], sh = ssl[64 + lane];

    for (int rr = 0; rr < 64; rr += 2) {
        int lr0 = w * 64 + rr;
        int n0 = r0 + lr0;
        if (n0 >= N) break;
        const unsigned* row0 = tile + lr0 * 32;
        const unsigned* row1 = row0 + 32;
        float o0 = 0.f, o1 = 0.f;
#pragma unroll
        for (int kp = 0; kp < 32; kp++) {
            unsigned u0 = row0[kp], u1 = row1[kp];
            o0 = fmaf(bf2f(u0 & 0xFFFFu), wcol[2 * kp], o0);
            o0 = fmaf(bf2f(u0 >> 16), wcol[2 * kp + 1], o0);
            o1 = fmaf(bf2f(u1 & 0xFFFFu), wcol[2 * kp], o1);
            o1 = fmaf(bf2f(u1 >> 16), wcol[2 * kp + 1], o1);
        }
        o0 = fmaxf(fmaf(o0, sc, sh), 0.f);
        o1 = fmaxf(fmaf(o1, sc, sh), 0.f);
        out[(size_t)n0 * 64 + lane] = o0;
        if (n0 + 1 < N) out[(size_t)(n0 + 1) * 64 + lane] = o1;
    }
}

extern "C" void kernel_launch(void* const* d_in, const int* in_sizes, int n_in,
                              void* d_out, int out_size, void* d_ws, size_t ws_size,
                              hipStream_t stream) {
    const float* x = (const float*)d_in[0];
    const int* ei = (const int*)d_in[1];
    const float* W = (const float*)d_in[2];
    // d_in[3] = bias: cancels inside BatchNorm, unused.
    const float* gamma = (const float*)d_in[4];
    const float* beta = (const float*)d_in[5];
    float* out = (float*)d_out;

    const int N = in_sizes[0] / 64;
    const int E = in_sizes[1] / 2;
    const int* src = ei;
    const int* dst = ei + E;
    const int NB = (N + 255) / 256;             // 391
    const int B = (N + NPB - 1) >> NPB_SHIFT;   // 13 coarse buckets
    const int SUBTOT = B * 64;                  // 832 sub-buckets (<=1024)
    // Slack capacity per coarse bucket: mean bucket count is E*8192/N ~= 131K,
    // sigma ~= 350. E/12 + 16384 ~= mean + 53 sigma -> overflow impossible.
    const int cap = E / 12 + 16384;

    char* ws = (char*)d_ws;
    size_t o = 0;
    float* stats = (float*)(ws + o); o += 512;       // zeroed in k_scanSub
    int* cnt2 = (int*)(ws + o); o += 4096;           // 832 ints used
    int* bcnt = (int*)(ws + o); o += 64;             // 13 coarse cursors
    size_t z0 = 512, z1 = 4096 + 64;                 // memset covers cnt2+bcnt
    int* sbase = (int*)(ws + o); o += 3584;          // SUBTOT+1 ints
    int* scur = (int*)(ws + o); o += 3584;
    int* deg = (int*)(ws + o); o += (size_t)4 * N;
    int* offs = (int*)(ws + o); o += (size_t)4 * N;
    float* dinv = (float*)(ws + o); o += (size_t)4 * N;
    unsigned short* xb2 = (unsigned short*)(ws + o); o += (size_t)128 * (N + 1);
    unsigned* aggb32 = (unsigned*)(ws + o); o += (size_t)128 * N;
    unsigned* binned = (unsigned*)(ws + o); o += (size_t)4 * B * cap;
    unsigned* sorted2 = (unsigned*)(ws + o); o += (size_t)4 * E;
    int* csr = (int*)binned;  // alias: binned consumed by k_sub before k_csr

    hipMemsetAsync(ws + z0, 0, z1, stream);

    const int EB = (E + 4095) / 4096;            // 391 binning blocks
    k_pre<<<EB, 256, 0, stream>>>(src, dst, cnt2, bcnt, binned, E, SUBTOT, cap);
    k_scanSub<<<1, 1024, 0, stream>>>(cnt2, sbase, scur, stats,
                                      (unsigned*)(xb2 + (size_t)N * 64),
                                      SUBTOT, E);
    k_sub<<<B * 32, 256, 0, stream>>>(binned, sbase, scur, sorted2, cap, B);
    k_csr<<<SUBTOT, 256, 0, stream>>>(sorted2, sbase, x, deg, dinv, offs, csr,
                                      xb2, N);
    k_agg<<<2048, 256, 0, stream>>>(offs, deg, csr, xb2, dinv, aggb32, N);
    k_gemm1<<<NB, 256, 0, stream>>>(aggb32, W, stats, N);
    k_gemm2<<<NB, 256, 0, stream>>>(aggb32, W, stats, gamma, beta, out, N,
                                    1.0f / (float)N);
}

// Round 4
// 223.378 us; speedup vs baseline: 1.1303x; 1.1303x over previous
//
#include <hip/hip_runtime.h>
#include <hip/hip_bf16.h>

#ifndef BN_EPS
#define BN_EPS 1e-5f
#endif

// ---------------------------------------------------------------------------
// N=100000, C=64, E=1600000.
// R15: collapse the 3-level sort to a single direct binning pass.
//   R14 post-mortem: k_agg (~50us) is at its random-gather floor; the other
//   ~200us is sort passes + dispatch overhead. k_agg needs no DENSE csr --
//   only offs/deg pointing somewhere. So bin edges directly into 782
//   slack-capacity sub-bucket regions (128 nodes each, cap=3072 = mean+22
//   sigma) with global atomic cursors; k_csr stages its window in LDS and
//   scatters IN PLACE (csr aliases binned), offs[n] = s*cap + lbase.
//   Deletes k_scanSub (1-block GPU bubble) and k_sub (full E-pass) entirely.
//   stats + zero-row zeroing folded into k_pre block 0.
// 6 dispatches: memset(cnt2), pre(direct bin), csr(+conv), agg, gemm1, gemm2.
// bias cancels inside BatchNorm, skipped.
// ---------------------------------------------------------------------------

#define CAP2 3072  // per-sub-bucket slack capacity (mean 2049, sigma 45)

__device__ __forceinline__ unsigned short f2bf(float f) {
    unsigned u = __float_as_uint(f);
    u += 0x7FFF + ((u >> 16) & 1);  // round-to-nearest-even
    return (unsigned short)(u >> 16);
}
__device__ __forceinline__ float bf2f(unsigned v) {
    return __uint_as_float(v << 16);
}

// Direct 782-bucket binning: per-block LDS histogram -> in-LDS scan (for
// block-local grouping) -> one global atomicAdd per nonempty bucket to
// reserve space -> grouped flush. Edge format: src | (d&127)<<17 (24 bits).
// Block 0 also zeroes stats[128] and the xb2 zero row.
__global__ __launch_bounds__(256) void k_pre(const int* __restrict__ src,
                                             const int* __restrict__ dst,
                                             int* __restrict__ cnt2,
                                             unsigned* __restrict__ binned,
                                             float* __restrict__ stats,
                                             unsigned* __restrict__ xbz,
                                             int E, int SUB) {
    __shared__ int h2[1024];        // counts -> inclusive scan
    __shared__ int gbase[784];      // global base per sub-bucket
    __shared__ int hcur[784];       // local cursor (starts at local excl)
    __shared__ unsigned lout[4096];
    __shared__ unsigned short lb[4096];
    int tid = threadIdx.x;
    if (blockIdx.x == 0) {
        if (tid < 128) stats[tid] = 0.f;
        if (tid < 32) xbz[tid] = 0u;
    }
    int c0 = blockIdx.x * 4096;
    if (c0 >= E) return;
    int cnt = min(4096, E - c0);
    for (int i = tid; i < 1024; i += 256) h2[i] = 0;
    __syncthreads();
    for (int i = tid; i < cnt; i += 256)
        atomicAdd(&h2[dst[c0 + i] >> 7], 1);
    __syncthreads();
    // inclusive scan of h2[0..1024) with 256 threads (read-all/write-all)
    for (int off = 1; off < 1024; off <<= 1) {
        int t0 = tid, t1 = tid + 256, t2 = tid + 512, t3 = tid + 768;
        int a0 = (t0 >= off) ? h2[t0 - off] : 0;
        int a1 = (t1 >= off) ? h2[t1 - off] : 0;
        int a2 = (t2 >= off) ? h2[t2 - off] : 0;
        int a3 = (t3 >= off) ? h2[t3 - off] : 0;
        __syncthreads();
        h2[t0] += a0; h2[t1] += a1; h2[t2] += a2; h2[t3] += a3;
        __syncthreads();
    }
    // reserve global space per nonempty sub-bucket; init local cursors
    for (int s2 = tid; s2 < SUB; s2 += 256) {
        int prev = s2 ? h2[s2 - 1] : 0;
        int v = h2[s2] - prev;
        hcur[s2] = prev;
        if (v > 0) gbase[s2] = atomicAdd(&cnt2[s2], v);
    }
    __syncthreads();
    // pack into LDS grouped by sub-bucket
    for (int i = tid; i < cnt; i += 256) {
        int d = dst[c0 + i];
        int s = src[c0 + i];
        int sb = d >> 7;
        unsigned packed = (unsigned)s | ((unsigned)(d & 127) << 17);
        int p = atomicAdd(&hcur[sb], 1);
        lout[p] = packed;
        lb[p] = (unsigned short)sb;
    }
    __syncthreads();
    // grouped flush: run for sub-bucket sb sits at [excl, excl+v) in lout
    for (int i = tid; i < cnt; i += 256) {
        int sb = lb[i];
        int hx = sb ? h2[sb - 1] : 0;  // local exclusive base
        binned[(size_t)sb * CAP2 + gbase[sb] + (i - hx)] = lout[i];
    }
}

// One block per 128-node sub-bucket: stage window in LDS, LDS histogram ->
// deg/dinv/offs, scatter csr IN PLACE over the binned region (node-ordered),
// then convert this block's 128 rows: xb2[n] = bf16(dinv[n]*x[n]).
__global__ __launch_bounds__(256) void k_csr(const int* __restrict__ cnt2,
                                             const float* __restrict__ x,
                                             unsigned* __restrict__ binned,
                                             int* __restrict__ deg,
                                             float* __restrict__ dinv,
                                             int* __restrict__ offs,
                                             unsigned short* __restrict__ xb2,
                                             int N) {
    __shared__ int hist[128], lbase[128], lcur[128];
    __shared__ float sdinv[128];
    __shared__ unsigned win[CAP2];
    int s = blockIdx.x;
    int tid = threadIdx.x;
    int cnt = cnt2[s];
    unsigned* bb = binned + (size_t)s * CAP2;
    for (int j = tid; j < cnt; j += 256) win[j] = bb[j];
    if (tid < 128) { hist[tid] = 0; lcur[tid] = 0; }
    __syncthreads();
    for (int j = tid; j < cnt; j += 256)
        atomicAdd(&hist[win[j] >> 17], 1);
    __syncthreads();
    if (tid == 0) {
        int acc = 0;
        for (int k = 0; k < 128; k++) { lbase[k] = acc; acc += hist[k]; }
    }
    __syncthreads();
    if (tid < 128) {  // deg / dinv / offs for this sub-bucket's 128 nodes
        int n = (s << 7) + tid;
        float dn = rsqrtf((float)(hist[tid] + 1));  // +1 = self-loop
        sdinv[tid] = dn;
        if (n < N) {
            deg[n] = hist[tid];
            dinv[n] = dn;
            offs[n] = s * CAP2 + lbase[tid];
        }
    }
    __syncthreads();
    // in-place scatter: reads fully staged in win, writes node-ordered
    for (int j = tid; j < cnt; j += 256) {
        unsigned e = win[j];
        int ld = e >> 17;
        bb[lbase[ld] + atomicAdd(&lcur[ld], 1)] = e & 0x1FFFFu;
    }
    // convert this block's 128 rows (streaming 32KB read, 16KB write)
    int base = s << 11;  // s*128 nodes * 16 float4/row
    const float4* xp = (const float4*)x;
    ushort4* xbp = (ushort4*)xb2;
#pragma unroll
    for (int i = 0; i < 8; i++) {
        int idx = tid + 256 * i;
        int n = (s << 7) + (idx >> 4);
        if (n < N) {
            float dn = sdinv[idx >> 4];
            float4 v = xp[base + idx];
            ushort4 b;
            b.x = f2bf(v.x * dn); b.y = f2bf(v.y * dn);
            b.z = f2bf(v.z * dn); b.w = f2bf(v.w * dn);
            xbp[base + idx] = b;
        }
    }
}

// Wave per node. lane = (half h, channel-pair p): one 4B load = 2 channels of
// one of 2 edges. 16-edge groups, 8 gathers in flight. Rows pre-scaled by
// dinv[src] -> plain adds. Lanes >= cnt hold idx=N (zero row, L1-hot).
__global__ __launch_bounds__(256) void k_agg(const int* __restrict__ offs,
                                             const int* __restrict__ deg,
                                             const int* __restrict__ csr,
                                             const unsigned short* __restrict__ xb2,
                                             const float* __restrict__ dinv,
                                             unsigned* __restrict__ aggb32, int N) {
    int lane = threadIdx.x & 63;
    int p = lane & 31;   // channel pair (channels 2p, 2p+1)
    int h = lane >> 5;   // half: which edge of a pair this lane gathers
    int wid = (blockIdx.x * 256 + threadIdx.x) >> 6;
    int nw = (gridDim.x * 256) >> 6;
    const unsigned* xw = (const unsigned*)xb2;

    for (int n = wid; n < N; n += nw) {
        float dn = dinv[n];
        unsigned sv = xw[(size_t)n * 32 + p];  // pre-scaled self row
        float accx = (h == 0) ? bf2f(sv & 0xFFFFu) : 0.f;
        float accy = (h == 0) ? bf2f(sv >> 16) : 0.f;
        int j0 = offs[n];
        int j1 = j0 + deg[n];
        for (int jb = j0; jb < j1; jb += 64) {
            int cnt = min(64, j1 - jb);
            int idx = N;  // zero row for overshoot lanes
            if (lane < cnt) idx = csr[jb + lane];
            for (int j = 0; j < cnt; j += 16) {
                int s0 = __shfl(idx, j + 0 + h),  s1 = __shfl(idx, j + 2 + h);
                int s2 = __shfl(idx, j + 4 + h),  s3 = __shfl(idx, j + 6 + h);
                int s4 = __shfl(idx, j + 8 + h),  s5 = __shfl(idx, j + 10 + h);
                int s6 = __shfl(idx, j + 12 + h), s7 = __shfl(idx, j + 14 + h);
                unsigned v0 = xw[(size_t)s0 * 32 + p];
                unsigned v1 = xw[(size_t)s1 * 32 + p];
                unsigned v2 = xw[(size_t)s2 * 32 + p];
                unsigned v3 = xw[(size_t)s3 * 32 + p];
                unsigned v4 = xw[(size_t)s4 * 32 + p];
                unsigned v5 = xw[(size_t)s5 * 32 + p];
                unsigned v6 = xw[(size_t)s6 * 32 + p];
                unsigned v7 = xw[(size_t)s7 * 32 + p];
                accx += bf2f(v0 & 0xFFFFu); accy += bf2f(v0 >> 16);
                accx += bf2f(v1 & 0xFFFFu); accy += bf2f(v1 >> 16);
                accx += bf2f(v2 & 0xFFFFu); accy += bf2f(v2 >> 16);
                accx += bf2f(v3 & 0xFFFFu); accy += bf2f(v3 >> 16);
                accx += bf2f(v4 & 0xFFFFu); accy += bf2f(v4 >> 16);
                accx += bf2f(v5 & 0xFFFFu); accy += bf2f(v5 >> 16);
                accx += bf2f(v6 & 0xFFFFu); accy += bf2f(v6 >> 16);
                accx += bf2f(v7 & 0xFFFFu); accy += bf2f(v7 >> 16);
            }
        }
        accx += __shfl_xor(accx, 32);
        accy += __shfl_xor(accy, 32);
        if (h == 0) {
            unsigned o = (unsigned)f2bf(accx * dn) | ((unsigned)f2bf(accy * dn) << 16);
            aggb32[(size_t)n * 32 + p] = o;
        }
    }
}

// Stats pass: o = agg@W per row (same structure as k_gemm2, NO stores).
__global__ __launch_bounds__(256) void k_gemm1(const unsigned* __restrict__ aggb32,
                                               const float* __restrict__ W,
                                               float* __restrict__ stats, int N) {
    __shared__ unsigned tile[256 * 32];
    __shared__ float red[512];  // [2][4][64]
    int t = threadIdx.x;
    int lane = t & 63;
    int w = t >> 6;
    int r0 = blockIdx.x * 256;
    const uint4* gp = (const uint4*)(aggb32 + (size_t)r0 * 32);
#pragma unroll
    for (int i = 0; i < 8; i++) {
        int idx = t + 256 * i;
        int n = r0 + (idx >> 3);
        uint4 v = {0u, 0u, 0u, 0u};
        if (n < N) v = gp[idx];
        *(uint4*)(tile + idx * 4) = v;
    }
    float wcol[64];
#pragma unroll
    for (int k = 0; k < 64; k++) wcol[k] = W[k * 64 + lane];
    __syncthreads();

    float psum = 0.f, psq = 0.f;
    for (int rr = 0; rr < 64; rr += 2) {
        int lr0 = w * 64 + rr;
        int n0 = r0 + lr0;
        if (n0 >= N) break;
        const unsigned* row0 = tile + lr0 * 32;
        const unsigned* row1 = row0 + 32;
        float o0 = 0.f, o1 = 0.f;
#pragma unroll
        for (int kp = 0; kp < 32; kp++) {
            unsigned u0 = row0[kp], u1 = row1[kp];
            o0 = fmaf(bf2f(u0 & 0xFFFFu), wcol[2 * kp], o0);
            o0 = fmaf(bf2f(u0 >> 16), wcol[2 * kp + 1], o0);
            o1 = fmaf(bf2f(u1 & 0xFFFFu), wcol[2 * kp], o1);
            o1 = fmaf(bf2f(u1 >> 16), wcol[2 * kp + 1], o1);
        }
        psum += o0;
        psq = fmaf(o0, o0, psq);
        if (n0 + 1 < N) {
            psum += o1;
            psq = fmaf(o1, o1, psq);
        }
    }
    red[w * 64 + lane] = psum;
    red[256 + w * 64 + lane] = psq;
    __syncthreads();
    if (w == 0) {
        float s = red[lane] + red[64 + lane] + red[128 + lane] + red[192 + lane];
        atomicAdd(&stats[lane], s);
    } else if (w == 1) {
        float q = red[256 + lane] + red[320 + lane] + red[384 + lane] + red[448 + lane];
        atomicAdd(&stats[64 + lane], q);
    }
}

// out = BN(agg@W)+ReLU, BN scale/shift derived in-prologue from stats.
__global__ __launch_bounds__(256) void k_gemm2(const unsigned* __restrict__ aggb32,
                                               const float* __restrict__ W,
                                               const float* __restrict__ stats,
                                               const float* __restrict__ gamma,
                                               const float* __restrict__ beta,
                                               float* __restrict__ out, int N,
                                               float invN) {
    __shared__ unsigned tile[256 * 32];
    __shared__ float ssl[128];
    int t = threadIdx.x;
    int lane = t & 63;
    int w = t >> 6;
    int r0 = blockIdx.x * 256;
    const uint4* gp = (const uint4*)(aggb32 + (size_t)r0 * 32);
#pragma unroll
    for (int i = 0; i < 8; i++) {
        int idx = t + 256 * i;
        int n = r0 + (idx >> 3);
        uint4 v = {0u, 0u, 0u, 0u};
        if (n < N) v = gp[idx];
        *(uint4*)(tile + idx * 4) = v;
    }
    if (t < 64) {  // bnprep folded in (redundant per block, trivial)
        float mean = stats[t] * invN;
        float var = stats[64 + t] * invN - mean * mean;  // biased var
        float sc = gamma[t] * rsqrtf(var + BN_EPS);
        ssl[t] = sc;
        ssl[64 + t] = beta[t] - mean * sc;
    }
    float wcol[64];
#pragma unroll
    for (int k = 0; k < 64; k++) wcol[k] = W[k * 64 + lane];
    __syncthreads();
    float sc = ssl[lane], sh = ssl[64 + lane];

    for (int rr = 0; rr < 64; rr += 2) {
        int lr0 = w * 64 + rr;
        int n0 = r0 + lr0;
        if (n0 >= N) break;
        const unsigned* row0 = tile + lr0 * 32;
        const unsigned* row1 = row0 + 32;
        float o0 = 0.f, o1 = 0.f;
#pragma unroll
        for (int kp = 0; kp < 32; kp++) {
            unsigned u0 = row0[kp], u1 = row1[kp];
            o0 = fmaf(bf2f(u0 & 0xFFFFu), wcol[2 * kp], o0);
            o0 = fmaf(bf2f(u0 >> 16), wcol[2 * kp + 1], o0);
            o1 = fmaf(bf2f(u1 & 0xFFFFu), wcol[2 * kp], o1);
            o1 = fmaf(bf2f(u1 >> 16), wcol[2 * kp + 1], o1);
        }
        o0 = fmaxf(fmaf(o0, sc, sh), 0.f);
        o1 = fmaxf(fmaf(o1, sc, sh), 0.f);
        out[(size_t)n0 * 64 + lane] = o0;
        if (n0 + 1 < N) out[(size_t)(n0 + 1) * 64 + lane] = o1;
    }
}

extern "C" void kernel_launch(void* const* d_in, const int* in_sizes, int n_in,
                              void* d_out, int out_size, void* d_ws, size_t ws_size,
                              hipStream_t stream) {
    const float* x = (const float*)d_in[0];
    const int* ei = (const int*)d_in[1];
    const float* W = (const float*)d_in[2];
    // d_in[3] = bias: cancels inside BatchNorm, unused.
    const float* gamma = (const float*)d_in[4];
    const float* beta = (const float*)d_in[5];
    float* out = (float*)d_out;

    const int N = in_sizes[0] / 64;
    const int E = in_sizes[1] / 2;
    const int* src = ei;
    const int* dst = ei + E;
    const int NB = (N + 255) / 256;        // 391
    const int SUB = (N + 127) >> 7;        // 782 sub-buckets of 128 nodes
    // Per-sub-bucket count ~ Binomial(E, 128/N): mean 2049, sigma 45.
    // CAP2=3072 = mean + 22.6 sigma -> overflow impossible.

    char* ws = (char*)d_ws;
    size_t o = 0;
    float* stats = (float*)(ws + o); o += 512;     // zeroed in k_pre block 0
    int* cnt2 = (int*)(ws + o); o += 4096;         // SUB ints, zeroed by memset
    int* deg = (int*)(ws + o); o += (size_t)4 * N;
    int* offs = (int*)(ws + o); o += (size_t)4 * N;
    float* dinv = (float*)(ws + o); o += (size_t)4 * N;
    unsigned short* xb2 = (unsigned short*)(ws + o); o += (size_t)128 * (N + 1);
    unsigned* aggb32 = (unsigned*)(ws + o); o += (size_t)128 * N;
    unsigned* binned = (unsigned*)(ws + o); o += (size_t)4 * SUB * CAP2;
    // csr aliases binned: k_csr scatters in place (window staged in LDS).

    hipMemsetAsync(cnt2, 0, 4096, stream);

    const int EB = (E + 4095) / 4096;      // 391 binning blocks
    k_pre<<<EB, 256, 0, stream>>>(src, dst, cnt2, binned, stats,
                                  (unsigned*)(xb2 + (size_t)N * 64), E, SUB);
    k_csr<<<SUB, 256, 0, stream>>>(cnt2, x, binned, deg, dinv, offs, xb2, N);
    k_agg<<<2048, 256, 0, stream>>>(offs, deg, (const int*)binned, xb2, dinv,
                                    aggb32, N);
    k_gemm1<<<NB, 256, 0, stream>>>(aggb32, W, stats, N);
    k_gemm2<<<NB, 256, 0, stream>>>(aggb32, W, stats, gamma, beta, out, N,
                                    1.0f / (float)N);
}